// Round 17
// baseline (159.586 us; speedup 1.0000x reference)
//
#include <hip/hip_runtime.h>
#include <hip/hip_bf16.h>

typedef _Float16 f16;
typedef __attribute__((ext_vector_type(4))) float f32x4;
typedef __attribute__((ext_vector_type(8))) _Float16 f16x8;
typedef __attribute__((ext_vector_type(4))) _Float16 f16x4;
typedef __attribute__((ext_vector_type(2))) __fp16 hf2;

#define Bv 2
#define Nv 2048
#define DIMv 1024
#define Hv 16
#define DHv 64
#define INNERv 1024
#define QKV3v 3072

__device__ __forceinline__ void gload16(const void* g, void* l) {
  __builtin_amdgcn_global_load_lds(
      (const __attribute__((address_space(1))) void*)g,
      (__attribute__((address_space(3))) void*)l, 16, 0, 0);
}

// ---------------- LayerNorm: fp32 in -> f16 out ----------------
__global__ __launch_bounds__(256) void ln_kernel(
    const float* __restrict__ x, const float* __restrict__ g,
    const float* __restrict__ bb, f16* __restrict__ h) {
  const int row = blockIdx.x;
  const int t = threadIdx.x;
  const float4 v = reinterpret_cast<const float4*>(x + (size_t)row * DIMv)[t];
  float s = v.x + v.y + v.z + v.w;
  float sq = v.x * v.x + v.y * v.y + v.z * v.z + v.w * v.w;
#pragma unroll
  for (int o = 32; o > 0; o >>= 1) {
    s += __shfl_down(s, o);
    sq += __shfl_down(sq, o);
  }
  __shared__ float red[8];
  __shared__ float musr[2];
  const int wave = t >> 6, lane = t & 63;
  if (lane == 0) { red[wave] = s; red[4 + wave] = sq; }
  __syncthreads();
  if (t == 0) {
    const float S = red[0] + red[1] + red[2] + red[3];
    const float SQ = red[4] + red[5] + red[6] + red[7];
    const float mu = S * (1.0f / DIMv);
    const float var = SQ * (1.0f / DIMv) - mu * mu;
    musr[0] = mu;
    musr[1] = rsqrtf(var + 1e-5f);
  }
  __syncthreads();
  const float mu = musr[0], rs = musr[1];
  const float4 gv = reinterpret_cast<const float4*>(g)[t];
  const float4 bv = reinterpret_cast<const float4*>(bb)[t];
  f16x4 o;
  o.x = (f16)((v.x - mu) * rs * gv.x + bv.x);
  o.y = (f16)((v.y - mu) * rs * gv.y + bv.y);
  o.z = (f16)((v.z - mu) * rs * gv.z + bv.z);
  o.w = (f16)((v.w - mu) * rs * gv.w + bv.w);
  *reinterpret_cast<f16x4*>(&h[(size_t)row * DIMv + t * 4]) = o;
}

// ------------- Precompute cos/sin of rotary freqs -----------
__global__ __launch_bounds__(256) void rotcs_kernel(
    const float* __restrict__ rot, float* __restrict__ c,
    float* __restrict__ s, int n) {
  const int i = blockIdx.x * blockDim.x + threadIdx.x;
  if (i < n) {
    const float f = rot[i];
    c[i] = cosf(f);
    s[i] = sinf(f);
  }
}

// ------------- Transpose + convert: W[K][N] fp32 -> Wt[N][K] f16 -----------
__global__ __launch_bounds__(256) void transpose_f16(
    const float* __restrict__ W, f16* __restrict__ Wt, int K, int N) {
  __shared__ float tile[64][65];
  const int t = threadIdx.x;
  const int n0 = blockIdx.x * 64, k0 = blockIdx.y * 64;
#pragma unroll
  for (int i = 0; i < 16; ++i) {
    const int idx = t + i * 256;
    const int r = idx >> 6, c = idx & 63;
    tile[r][c] = W[(size_t)(k0 + r) * N + n0 + c];
  }
  __syncthreads();
#pragma unroll
  for (int i = 0; i < 16; ++i) {
    const int idx = t + i * 256;
    const int r = idx >> 6, c = idx & 63;
    Wt[(size_t)(n0 + r) * K + k0 + c] = (f16)tile[c][r];
  }
}

// ------- f16 MFMA GEMM, 128x128 tile, BK=32, counted-vmcnt pipeline -------
// EPI=0: fp32 plain out. EPI=2: fused rotary + scatter to qkvf/Kimg/Vimg.
template <int EPI>
__global__ __launch_bounds__(256) void gemm_mfma(
    const f16* __restrict__ A, const f16* __restrict__ Bt,
    const float* __restrict__ bias, void* __restrict__ Cout,
    const float* __restrict__ cs, const float* __restrict__ sn,
    f16* __restrict__ qkvf, f16* __restrict__ Kimg, f16* __restrict__ Vimg,
    int M, int N, int K) {
  __shared__ __align__(16) f16 Asb[2][128 * 32];
  __shared__ __align__(16) f16 Bsb[2][128 * 32];
  const int t = threadIdx.x;
  const int l = t & 63, w = t >> 6;
  const int wr = w >> 1, wc = w & 1;
  const int row0 = blockIdx.y * 128, col0 = blockIdx.x * 128;

  const int i1 = t, i2 = t + 256;
  const f16* ga1 = &A[(size_t)(row0 + (i1 >> 2)) * K + (i1 & 3) * 8];
  const f16* ga2 = &A[(size_t)(row0 + (i2 >> 2)) * K + (i2 & 3) * 8];
  const f16* gb1 = &Bt[(size_t)(col0 + (i1 >> 2)) * K + (i1 & 3) * 8];
  const f16* gb2 = &Bt[(size_t)(col0 + (i2 >> 2)) * K + (i2 & 3) * 8];
  const int a_off1 = w * 512, a_off2 = w * 512 + 2048;

  const int rl = l & 15, kg = l >> 4;
  const int ar = (wr * 64 + rl) * 32 + kg * 8;
  const int br = (wc * 64 + rl) * 32 + kg * 8;

  const f32x4 zero = {0.f, 0.f, 0.f, 0.f};
  f32x4 acc[4][4];
#pragma unroll
  for (int m = 0; m < 4; ++m)
#pragma unroll
    for (int n = 0; n < 4; ++n) acc[m][n] = zero;

#define GSTAGE(buf, kk)                           \
  {                                               \
    gload16(ga1 + (kk)*32, &Asb[buf][a_off1]);    \
    gload16(ga2 + (kk)*32, &Asb[buf][a_off2]);    \
    gload16(gb1 + (kk)*32, &Bsb[buf][a_off1]);    \
    gload16(gb2 + (kk)*32, &Bsb[buf][a_off2]);    \
  }

  const int nt = K >> 5;
  GSTAGE(0, 0);

  for (int kt = 0; kt < nt; ++kt) {
    const int cur = kt & 1;
    if (kt + 1 < nt) {
      GSTAGE(cur ^ 1, kt + 1);
      asm volatile("s_waitcnt vmcnt(4)" ::: "memory");
    } else {
      asm volatile("s_waitcnt vmcnt(0)" ::: "memory");
    }
    __builtin_amdgcn_s_barrier();
    __builtin_amdgcn_sched_barrier(0);
    f16x8 af[4], bf[4];
#pragma unroll
    for (int m = 0; m < 4; ++m)
      af[m] = *reinterpret_cast<const f16x8*>(&Asb[cur][ar + m * 16 * 32]);
#pragma unroll
    for (int n = 0; n < 4; ++n)
      bf[n] = *reinterpret_cast<const f16x8*>(&Bsb[cur][br + n * 16 * 32]);
#pragma unroll
    for (int m = 0; m < 4; ++m)
#pragma unroll
      for (int n = 0; n < 4; ++n)
        acc[m][n] =
            __builtin_amdgcn_mfma_f32_16x16x32_f16(af[m], bf[n], acc[m][n], 0, 0, 0);
    asm volatile("" ::: "memory");
    __builtin_amdgcn_s_barrier();
    __builtin_amdgcn_sched_barrier(0);
  }
#undef GSTAGE

  if (EPI == 0) {
#pragma unroll
    for (int m = 0; m < 4; ++m) {
#pragma unroll
      for (int n = 0; n < 4; ++n) {
#pragma unroll
        for (int jr = 0; jr < 4; ++jr) {
          const int rg = row0 + wr * 64 + m * 16 + kg * 4 + jr;
          const int cg = col0 + wc * 64 + n * 16 + rl;
          ((float*)Cout)[(size_t)rg * N + cg] = acc[m][n][jr] + bias[cg];
        }
      }
    }
  } else {
    // fused rotary + scatter: q->qkvf, k->Kimg (swizzled), v->Vimg (key'-perm)
    const int slab = col0 >> 10;  // block-uniform: 0=q, 1=k, 2=v
    const int b = row0 >> 11;     // block-uniform
    const int ntile = ((row0 & 2047) >> 6) + wr;
#pragma unroll
    for (int m = 0; m < 4; ++m) {
      const int key0 = m * 16 + kg * 4;  // key = key0 + jr (rg mod 64)
      const int rgb = row0 + wr * 64 + key0;
#pragma unroll
      for (int n = 0; n < 4; ++n) {
        const int cg = col0 + wc * 64 + n * 16 + rl;
        const int d = cg & 63;
        const int hh = (cg >> 6) & 15;
        float y[4];
#pragma unroll
        for (int jr = 0; jr < 4; ++jr) {
          const float v = acc[m][n][jr] + bias[cg];
          const float p = __shfl_xor(v, 1);
          const size_t cb = (size_t)(rgb + jr) * DHv + d;
          const float cc = cs[cb], ss = sn[cb];
          // forward rotary: even d: v*c - p*s ; odd d: v*c + p*s
          y[jr] = (l & 1) ? (v * cc + p * ss) : (v * cc - p * ss);
        }
        if (slab == 0) {
#pragma unroll
          for (int jr = 0; jr < 4; ++jr)
            qkvf[(size_t)(rgb + jr) * QKV3v + cg] = (f16)y[jr];
        } else if (slab == 1) {
          const size_t tb = ((size_t)((b * Hv + hh) * 32 + ntile)) << 12;
#pragma unroll
          for (int jr = 0; jr < 4; ++jr) {
            const int key = key0 + jr;
            Kimg[tb + key * 64 + (d ^ ((key & 7) << 3))] = (f16)y[jr];
          }
        } else {
          const size_t tb = ((size_t)((b * Hv + hh) * 32 + ntile)) << 12;
          const int kp = ((m & 2) << 4) | (kg << 3);  // key' & ~7
          f16x4 pk;
          pk.x = (f16)y[0];
          pk.y = (f16)y[1];
          pk.z = (f16)y[2];
          pk.w = (f16)y[3];
          *reinterpret_cast<f16x4*>(
              &Vimg[tb + d * 64 + (kp ^ ((d & 7) << 3)) + ((m & 1) << 2)]) = pk;
        }
      }
    }
  }
}

// --- MFMA flash attention v8: Q-tile 128, 8 waves, 3-buffer ring depth-2
// prefetch, image gload_lds staging, swapped QK^T, register P, l via
// ones-MFMA, O^T epilogue (3-step exchange).
__global__ __launch_bounds__(512, 4) void attn_mfma(
    const f16* __restrict__ qkvf, const f16* __restrict__ Kimg,
    const f16* __restrict__ Vimg, const float* __restrict__ cs,
    const float* __restrict__ sn, f16* __restrict__ ao) {
  const int wg = blockIdx.x;
  const int swz = (wg & 7) * 64 + (wg >> 3);  // XCD-contiguous remap (512=8*64)
  const int qb = swz & 15;
  const int hh = (swz >> 4) & 15;
  const int b = swz >> 8;
  const int t = threadIdx.x, l = t & 63, w = t >> 6;
  const int qw = w >> 1, kw = w & 1;
  const int rl = l & 15, kg = l >> 4;

  __shared__ __align__(16) f16 KsB[3][4096];
  __shared__ __align__(16) f16 VtB[3][4096];
  __shared__ float Lbuf[4][2][32];

  const size_t qrow0 = (size_t)(b * Nv + qb * 128 + qw * 32);
  f16x8 bq[2][2];
#pragma unroll
  for (int nq = 0; nq < 2; ++nq)
#pragma unroll
    for (int ks = 0; ks < 2; ++ks)
      bq[nq][ks] = *reinterpret_cast<const f16x8*>(
          &qkvf[(qrow0 + nq * 16 + rl) * QKV3v + hh * DHv + ks * 32 + kg * 8]);

  f16x8 ones;
#pragma unroll
  for (int j = 0; j < 8; ++j) ones[j] = (f16)1.0f;

  const f32x4 zero = {0.f, 0.f, 0.f, 0.f};
  f32x4 o_acc[2][4];
  f32x4 l_acc[2] = {zero, zero};
#pragma unroll
  for (int nq = 0; nq < 2; ++nq)
#pragma unroll
    for (int m2 = 0; m2 < 4; ++m2) o_acc[nq][m2] = zero;

  const size_t ibase = (((size_t)((b * Hv + hh) * 32)) << 12) + w * 512 + l * 8;
  const f16* kimg_t = Kimg + ibase;
  const f16* vimg_t = Vimg + ibase;

#define STAGEI(buf, tile)                                         \
  {                                                               \
    gload16(kimg_t + ((size_t)(tile) << 12), &KsB[buf][w * 512]); \
    gload16(vimg_t + ((size_t)(tile) << 12), &VtB[buf][w * 512]); \
  }

  STAGEI(0, 0);
  STAGEI(1, 1);

  const float SC2 = 0.125f * 1.44269504f;

  int cur = 0;
  for (int kt = 0; kt < 32; ++kt) {
    if (kt < 30) {
      int stg = cur + 2;
      if (stg >= 3) stg -= 3;
      STAGEI(stg, kt + 2);
      asm volatile("s_waitcnt vmcnt(4)" ::: "memory");
    } else if (kt == 30) {
      asm volatile("s_waitcnt vmcnt(2)" ::: "memory");
    } else {
      asm volatile("s_waitcnt vmcnt(0)" ::: "memory");
    }
    __builtin_amdgcn_s_barrier();
    __builtin_amdgcn_sched_barrier(0);

    const f16* Kc = &KsB[cur][0];
    const f16* Vc = &VtB[cur][0];

    f16x8 ak[2][2];
#pragma unroll
    for (int mk = 0; mk < 2; ++mk)
#pragma unroll
      for (int ks = 0; ks < 2; ++ks)
        ak[mk][ks] = *reinterpret_cast<const f16x8*>(
            &Kc[((kw * 32 + mk * 16 + rl) << 6) |
                ((ks * 32 + kg * 8) ^ ((rl & 7) << 3))]);
    f16x8 av[4];
#pragma unroll
    for (int m2 = 0; m2 < 4; ++m2)
      av[m2] = *reinterpret_cast<const f16x8*>(
          &Vc[((m2 * 16 + rl) << 6) |
              ((kw * 32 + kg * 8) ^ ((rl & 7) << 3))]);

    f32x4 sa[2][2];
#pragma unroll
    for (int mk = 0; mk < 2; ++mk)
#pragma unroll
      for (int nq = 0; nq < 2; ++nq) sa[mk][nq] = zero;
    __builtin_amdgcn_s_setprio(1);
#pragma unroll
    for (int ks = 0; ks < 2; ++ks)
#pragma unroll
      for (int mk = 0; mk < 2; ++mk)
#pragma unroll
        for (int nq = 0; nq < 2; ++nq)
          sa[mk][nq] = __builtin_amdgcn_mfma_f32_16x16x32_f16(
              ak[mk][ks], bq[nq][ks], sa[mk][nq], 0, 0, 0);
    __builtin_amdgcn_s_setprio(0);

    f16x8 pb[2];
#pragma unroll
    for (int nq = 0; nq < 2; ++nq) {
      float p00 = exp2f(fminf(sa[0][nq][0] * SC2, 13.0f));
      float p01 = exp2f(fminf(sa[0][nq][1] * SC2, 13.0f));
      float p02 = exp2f(fminf(sa[0][nq][2] * SC2, 13.0f));
      float p03 = exp2f(fminf(sa[0][nq][3] * SC2, 13.0f));
      float p10 = exp2f(fminf(sa[1][nq][0] * SC2, 13.0f));
      float p11 = exp2f(fminf(sa[1][nq][1] * SC2, 13.0f));
      float p12 = exp2f(fminf(sa[1][nq][2] * SC2, 13.0f));
      float p13 = exp2f(fminf(sa[1][nq][3] * SC2, 13.0f));
      union { hf2 h2[4]; f16x8 v; } u;
      u.h2[0] = __builtin_amdgcn_cvt_pkrtz(p00, p01);
      u.h2[1] = __builtin_amdgcn_cvt_pkrtz(p02, p03);
      u.h2[2] = __builtin_amdgcn_cvt_pkrtz(p10, p11);
      u.h2[3] = __builtin_amdgcn_cvt_pkrtz(p12, p13);
      pb[nq] = u.v;
    }

    __builtin_amdgcn_s_setprio(1);
#pragma unroll
    for (int nq = 0; nq < 2; ++nq)
      l_acc[nq] = __builtin_amdgcn_mfma_f32_16x16x32_f16(
          ones, pb[nq], l_acc[nq], 0, 0, 0);
#pragma unroll
    for (int nq = 0; nq < 2; ++nq)
#pragma unroll
      for (int m2 = 0; m2 < 4; ++m2)
        o_acc[nq][m2] = __builtin_amdgcn_mfma_f32_16x16x32_f16(
            av[m2], pb[nq], o_acc[nq][m2], 0, 0, 0);
    __builtin_amdgcn_s_setprio(0);

    asm volatile("" ::: "memory");
    __builtin_amdgcn_s_barrier();
    __builtin_amdgcn_sched_barrier(0);
    cur = (cur == 2) ? 0 : cur + 1;
  }
#undef STAGEI

  if (kg == 0) {
    Lbuf[qw][kw][rl] = l_acc[0][0];
    Lbuf[qw][kw][16 + rl] = l_acc[1][0];
  }
  char* ob = (qw < 2 ? (char*)KsB : (char*)VtB) + (qw & 1) * 8192;
  if (kw == 1) {
#pragma unroll
    for (int nq = 0; nq < 2; ++nq)
#pragma unroll
      for (int m2 = 0; m2 < 4; ++m2)
        *reinterpret_cast<f32x4*>(
            ob + (nq * 16 + rl) * 256 +
            ((m2 * 64 + kg * 16) ^ ((rl & 7) << 4))) = o_acc[nq][m2];
  }
  __syncthreads();
  if (kw == 0) {
#pragma unroll
    for (int nq = 0; nq < 2; ++nq)
#pragma unroll
      for (int m2 = 0; m2 < 4; ++m2) {
        f32x4* slot = reinterpret_cast<f32x4*>(
            ob + (nq * 16 + rl) * 256 +
            ((m2 * 64 + kg * 16) ^ ((rl & 7) << 4)));
        *slot = *slot + o_acc[nq][m2];
      }
  }
  __syncthreads();
  {
    const int q_local = w * 16 + (l >> 2);
    const int qw_r = q_local >> 5, q_in = q_local & 31;
    const int d0 = (l & 3) * 16;
    char* rb = (qw_r < 2 ? (char*)KsB : (char*)VtB) + (qw_r & 1) * 8192;
    const float linv = 1.0f / (Lbuf[qw_r][0][q_in] + Lbuf[qw_r][1][q_in]);
    const size_t nq_g = (size_t)(b * Nv + qb * 128 + q_local);
    const size_t cb = nq_g * DHv + d0;
    union { f16 e[16]; f16x8 v[2]; } uo;
#pragma unroll
    for (int j = 0; j < 4; ++j) {
      const unsigned off = q_in * 256 + (((l & 3) * 64 + j * 16) ^ ((q_in & 7) << 4));
      const f32x4 a = *reinterpret_cast<const f32x4*>(rb + off);
      const float4 csv = *reinterpret_cast<const float4*>(&cs[cb + j * 4]);
      const float4 snv = *reinterpret_cast<const float4*>(&sn[cb + j * 4]);
      const float o0 = a[0] * linv;
      const float o1 = a[1] * linv;
      const float o2 = a[2] * linv;
      const float o3 = a[3] * linv;
      uo.e[j * 4 + 0] = (f16)(o0 * csv.x + o1 * snv.x);
      uo.e[j * 4 + 1] = (f16)(o1 * csv.y - o0 * snv.y);
      uo.e[j * 4 + 2] = (f16)(o2 * csv.z + o3 * snv.z);
      uo.e[j * 4 + 3] = (f16)(o3 * csv.w - o2 * snv.w);
    }
    f16* aop = &ao[nq_g * INNERv + hh * DHv + d0];
    *reinterpret_cast<f16x8*>(aop) = uo.v[0];
    *reinterpret_cast<f16x8*>(aop + 8) = uo.v[1];
  }
}

extern "C" void kernel_launch(void* const* d_in, const int* in_sizes, int n_in,
                              void* d_out, int out_size, void* d_ws, size_t ws_size,
                              hipStream_t stream) {
  (void)in_sizes; (void)n_in; (void)out_size; (void)ws_size;
  const float* x = (const float*)d_in[0];
  const float* rot = (const float*)d_in[1];
  const float* ln_g = (const float*)d_in[2];
  const float* ln_b = (const float*)d_in[3];
  const float* w_qkv = (const float*)d_in[4];
  const float* b_qkv = (const float*)d_in[5];
  const float* w_out = (const float*)d_in[6];
  const float* b_out = (const float*)d_in[7];

  char* p = (char*)d_ws;
  f16* h = (f16*)p;            p += (size_t)Bv * Nv * DIMv * 2;
  float* cs = (float*)p;       p += (size_t)Bv * Nv * DHv * 4;
  float* sn = (float*)p;       p += (size_t)Bv * Nv * DHv * 4;
  f16* wqT = (f16*)p;          p += (size_t)QKV3v * DIMv * 2;
  f16* woT = (f16*)p;          p += (size_t)DIMv * INNERv * 2;
  f16* qkvf = (f16*)p;         p += (size_t)Bv * Nv * QKV3v * 2;
  f16* ao = (f16*)p;           p += (size_t)Bv * Nv * INNERv * 2;
  f16* Kimg = (f16*)p;         p += (size_t)Bv * Hv * 32 * 4096 * 2;
  f16* Vimg = (f16*)p;         p += (size_t)Bv * Hv * 32 * 4096 * 2;

  ln_kernel<<<dim3(Bv * Nv), dim3(256), 0, stream>>>(x, ln_g, ln_b, h);
  rotcs_kernel<<<dim3((Bv * Nv * DHv) / 256), dim3(256), 0, stream>>>(
      rot, cs, sn, Bv * Nv * DHv);
  transpose_f16<<<dim3(QKV3v / 64, DIMv / 64), dim3(256), 0, stream>>>(
      w_qkv, wqT, DIMv, QKV3v);
  transpose_f16<<<dim3(INNERv / 64, DIMv / 64), dim3(256), 0, stream>>>(
      w_out, woT, DIMv, INNERv);
  gemm_mfma<2><<<dim3(QKV3v / 128, (Bv * Nv) / 128), dim3(256), 0, stream>>>(
      h, wqT, b_qkv, nullptr, cs, sn, qkvf, Kimg, Vimg, Bv * Nv, QKV3v, DIMv);
  attn_mfma<<<dim3(512), dim3(512), 0, stream>>>(qkvf, Kimg, Vimg, cs, sn, ao);
  gemm_mfma<0><<<dim3(DIMv / 128, (Bv * Nv) / 128), dim3(256), 0, stream>>>(
      ao, woT, b_out, d_out, nullptr, nullptr, nullptr, nullptr, nullptr,
      Bv * Nv, DIMv, INNERv);
}

// Round 18
// 148.975 us; speedup vs baseline: 1.0712x; 1.0712x over previous
//
#include <hip/hip_runtime.h>
#include <hip/hip_bf16.h>

typedef _Float16 f16;
typedef __attribute__((ext_vector_type(4))) float f32x4;
typedef __attribute__((ext_vector_type(8))) _Float16 f16x8;
typedef __attribute__((ext_vector_type(4))) _Float16 f16x4;
typedef __attribute__((ext_vector_type(2))) __fp16 hf2;

#define Bv 2
#define Nv 2048
#define DIMv 1024
#define Hv 16
#define DHv 64
#define INNERv 1024
#define QKV3v 3072

__device__ __forceinline__ void gload16(const void* g, void* l) {
  __builtin_amdgcn_global_load_lds(
      (const __attribute__((address_space(1))) void*)g,
      (__attribute__((address_space(3))) void*)l, 16, 0, 0);
}

// ---------------- LayerNorm: fp32 in -> f16 out ----------------
__global__ __launch_bounds__(256) void ln_kernel(
    const float* __restrict__ x, const float* __restrict__ g,
    const float* __restrict__ bb, f16* __restrict__ h) {
  const int row = blockIdx.x;
  const int t = threadIdx.x;
  const float4 v = reinterpret_cast<const float4*>(x + (size_t)row * DIMv)[t];
  float s = v.x + v.y + v.z + v.w;
  float sq = v.x * v.x + v.y * v.y + v.z * v.z + v.w * v.w;
#pragma unroll
  for (int o = 32; o > 0; o >>= 1) {
    s += __shfl_down(s, o);
    sq += __shfl_down(sq, o);
  }
  __shared__ float red[8];
  __shared__ float musr[2];
  const int wave = t >> 6, lane = t & 63;
  if (lane == 0) { red[wave] = s; red[4 + wave] = sq; }
  __syncthreads();
  if (t == 0) {
    const float S = red[0] + red[1] + red[2] + red[3];
    const float SQ = red[4] + red[5] + red[6] + red[7];
    const float mu = S * (1.0f / DIMv);
    const float var = SQ * (1.0f / DIMv) - mu * mu;
    musr[0] = mu;
    musr[1] = rsqrtf(var + 1e-5f);
  }
  __syncthreads();
  const float mu = musr[0], rs = musr[1];
  const float4 gv = reinterpret_cast<const float4*>(g)[t];
  const float4 bv = reinterpret_cast<const float4*>(bb)[t];
  f16x4 o;
  o.x = (f16)((v.x - mu) * rs * gv.x + bv.x);
  o.y = (f16)((v.y - mu) * rs * gv.y + bv.y);
  o.z = (f16)((v.z - mu) * rs * gv.z + bv.z);
  o.w = (f16)((v.w - mu) * rs * gv.w + bv.w);
  *reinterpret_cast<f16x4*>(&h[(size_t)row * DIMv + t * 4]) = o;
}

// ------------- Precompute cos/sin of rotary freqs -----------
__global__ __launch_bounds__(256) void rotcs_kernel(
    const float* __restrict__ rot, float* __restrict__ c,
    float* __restrict__ s, int n) {
  const int i = blockIdx.x * blockDim.x + threadIdx.x;
  if (i < n) {
    const float f = rot[i];
    c[i] = cosf(f);
    s[i] = sinf(f);
  }
}

// ------------- Transpose + convert: W[K][N] fp32 -> Wt[N][K] f16 -----------
__global__ __launch_bounds__(256) void transpose_f16(
    const float* __restrict__ W, f16* __restrict__ Wt, int K, int N) {
  __shared__ float tile[64][65];
  const int t = threadIdx.x;
  const int n0 = blockIdx.x * 64, k0 = blockIdx.y * 64;
#pragma unroll
  for (int i = 0; i < 16; ++i) {
    const int idx = t + i * 256;
    const int r = idx >> 6, c = idx & 63;
    tile[r][c] = W[(size_t)(k0 + r) * N + n0 + c];
  }
  __syncthreads();
#pragma unroll
  for (int i = 0; i < 16; ++i) {
    const int idx = t + i * 256;
    const int r = idx >> 6, c = idx & 63;
    Wt[(size_t)(n0 + r) * K + k0 + c] = (f16)tile[c][r];
  }
}

// ---- QKV GEMM: 256x256 tile, BK=64, one barrier-pair per K-tile ----------
// 512 thr (8 waves, 2Mx4N). Counted vmcnt(8); both-sides XOR swizzle.
// Epilogue fuses rotary + scatter: q->qkvf, k->Kimg, v->Vimg.
__global__ __launch_bounds__(512) void gemm256_qkv(
    const f16* __restrict__ A, const f16* __restrict__ Bt,
    const float* __restrict__ bias, f16* __restrict__ qkvf,
    f16* __restrict__ Kimg, f16* __restrict__ Vimg,
    const float* __restrict__ cs, const float* __restrict__ sn) {
  __shared__ __align__(16) f16 Abuf[2][256 * 64];
  __shared__ __align__(16) f16 Bbuf[2][256 * 64];
  const int t = threadIdx.x, l = t & 63, w = t >> 6;
  const int wm = w >> 2, wn = w & 3;
  const int row0 = blockIdx.y * 256, col0 = blockIdx.x * 256;
  const int rl = l & 15, kg = l >> 4;

  const int srow = l >> 3;
  const int sgk = ((l & 7) ^ (srow & 7)) * 8;
  const f16* gA = &A[(size_t)(row0 + w * 32 + srow) * 1024 + sgk];
  const f16* gB = &Bt[(size_t)(col0 + w * 32 + srow) * 1024 + sgk];

  const f32x4 zero = {0.f, 0.f, 0.f, 0.f};
  f32x4 acc[8][4];
#pragma unroll
  for (int m = 0; m < 8; ++m)
#pragma unroll
    for (int n = 0; n < 4; ++n) acc[m][n] = zero;

#define STG(buf, kt)                                                         \
  {                                                                          \
    _Pragma("unroll") for (int i = 0; i < 4; ++i)                            \
        gload16(gA + (kt)*64 + i * 8 * 1024,                                 \
                &Abuf[buf][(w * 32 + i * 8) * 64]);                          \
    _Pragma("unroll") for (int i = 0; i < 4; ++i)                            \
        gload16(gB + (kt)*64 + i * 8 * 1024,                                 \
                &Bbuf[buf][(w * 32 + i * 8) * 64]);                          \
  }

  const int nkt = 16;  // K=1024 / 64
  STG(0, 0);

  for (int kt = 0; kt < nkt; ++kt) {
    const int cur = kt & 1;
    if (kt + 1 < nkt) {
      STG(cur ^ 1, kt + 1);
      asm volatile("s_waitcnt vmcnt(8)" ::: "memory");
    } else {
      asm volatile("s_waitcnt vmcnt(0)" ::: "memory");
    }
    __builtin_amdgcn_s_barrier();
    __builtin_amdgcn_sched_barrier(0);
#pragma unroll
    for (int kh = 0; kh < 2; ++kh) {
      f16x8 bf[4], af[8];
#pragma unroll
      for (int n = 0; n < 4; ++n) {
        const int r = wn * 64 + n * 16 + rl;
        bf[n] = *reinterpret_cast<const f16x8*>(
            &Bbuf[cur][r * 64 + (((kh * 4 + kg) ^ (r & 7)) << 3)]);
      }
#pragma unroll
      for (int m = 0; m < 8; ++m) {
        const int r = wm * 128 + m * 16 + rl;
        af[m] = *reinterpret_cast<const f16x8*>(
            &Abuf[cur][r * 64 + (((kh * 4 + kg) ^ (r & 7)) << 3)]);
      }
      __builtin_amdgcn_s_setprio(1);
#pragma unroll
      for (int m = 0; m < 8; ++m)
#pragma unroll
        for (int n = 0; n < 4; ++n)
          acc[m][n] = __builtin_amdgcn_mfma_f32_16x16x32_f16(af[m], bf[n],
                                                             acc[m][n], 0, 0, 0);
      __builtin_amdgcn_s_setprio(0);
    }
    asm volatile("" ::: "memory");
    __builtin_amdgcn_s_barrier();
    __builtin_amdgcn_sched_barrier(0);
  }
#undef STG

  // ---- fused epilogue: rotary + scatter to qkvf / Kimg / Vimg ----
  const int slab = col0 >> 10;  // block-uniform: 0=q, 1=k, 2=v
  const int b = row0 >> 11;     // block-uniform
#pragma unroll
  for (int m = 0; m < 8; ++m) {
    const int rg = row0 + wm * 128 + m * 16 + kg * 4;  // +jr
    const int nt = (rg & 2047) >> 6;                   // jr-invariant
#pragma unroll
    for (int n = 0; n < 4; ++n) {
      const int cg = col0 + wn * 64 + n * 16 + rl;
      const int d = cg & 63;
      const int hh = (cg >> 6) & 15;
      float y[4];
#pragma unroll
      for (int jr = 0; jr < 4; ++jr) {
        const float v = acc[m][n][jr] + bias[cg];
        const float p = __shfl_xor(v, 1);
        const size_t cb = (size_t)(rg + jr) * DHv + d;
        const float cc = cs[cb], ss = sn[cb];
        // forward rotary: even d: v*c - p*s ; odd d: v*c + p*s
        y[jr] = (l & 1) ? (v * cc + p * ss) : (v * cc - p * ss);
      }
      if (slab == 0) {
#pragma unroll
        for (int jr = 0; jr < 4; ++jr)
          qkvf[(size_t)(rg + jr) * QKV3v + cg] = (f16)y[jr];
      } else if (slab == 1) {
        const size_t tb = ((size_t)((b * Hv + hh) * 32 + nt)) << 12;
#pragma unroll
        for (int jr = 0; jr < 4; ++jr) {
          const int key = ((m & 3) * 16 + kg * 4 + jr);
          Kimg[tb + key * 64 + (d ^ ((key & 7) << 3))] = (f16)y[jr];
        }
      } else {
        const size_t tb = ((size_t)((b * Hv + hh) * 32 + nt)) << 12;
        const int kp = ((m & 2) << 4) | (kg << 3);  // key' & ~7
        f16x4 pk;
        pk.x = (f16)y[0];
        pk.y = (f16)y[1];
        pk.z = (f16)y[2];
        pk.w = (f16)y[3];
        *reinterpret_cast<f16x4*>(
            &Vimg[tb + d * 64 + (kp ^ ((d & 7) << 3)) + ((m & 1) << 2)]) = pk;
      }
    }
  }
}

// ---- Output projection: 64x128 tile, BK=32, counted vmcnt(3) pipeline ----
// Grid 8x64 = 512 blocks (2/CU) -> inter-block overlap fills barrier stalls.
__global__ __launch_bounds__(256) void gemm_out64(
    const f16* __restrict__ A, const f16* __restrict__ Bt,
    const float* __restrict__ bias, float* __restrict__ C,
    int M, int N, int K) {
  __shared__ __align__(16) f16 Asb[2][64 * 32];   // 4 KB per buf
  __shared__ __align__(16) f16 Bsb[2][128 * 32];  // 8 KB per buf
  const int t = threadIdx.x;
  const int l = t & 63, w = t >> 6;
  const int wr = w >> 1, wc = w & 1;
  const int row0 = blockIdx.y * 64, col0 = blockIdx.x * 128;

  const f16* ga = &A[(size_t)(row0 + (t >> 2)) * K + (t & 3) * 8];
  const int i2 = t + 256;
  const f16* gb1 = &Bt[(size_t)(col0 + (t >> 2)) * K + (t & 3) * 8];
  const f16* gb2 = &Bt[(size_t)(col0 + (i2 >> 2)) * K + (i2 & 3) * 8];
  const int off1 = w * 512, off2 = w * 512 + 2048;

  const int rl = l & 15, kg = l >> 4;
  const int ar = (wr * 32 + rl) * 32 + kg * 8;
  const int br = (wc * 64 + rl) * 32 + kg * 8;

  const f32x4 zero = {0.f, 0.f, 0.f, 0.f};
  f32x4 acc[2][4];
#pragma unroll
  for (int m = 0; m < 2; ++m)
#pragma unroll
    for (int n = 0; n < 4; ++n) acc[m][n] = zero;

#define OSTAGE(buf, kk)                           \
  {                                               \
    gload16(ga + (kk)*32, &Asb[buf][off1]);       \
    gload16(gb1 + (kk)*32, &Bsb[buf][off1]);      \
    gload16(gb2 + (kk)*32, &Bsb[buf][off2]);      \
  }

  const int nt = K >> 5;
  OSTAGE(0, 0);

  for (int kt = 0; kt < nt; ++kt) {
    const int cur = kt & 1;
    if (kt + 1 < nt) {
      OSTAGE(cur ^ 1, kt + 1);
      asm volatile("s_waitcnt vmcnt(3)" ::: "memory");
    } else {
      asm volatile("s_waitcnt vmcnt(0)" ::: "memory");
    }
    __builtin_amdgcn_s_barrier();
    __builtin_amdgcn_sched_barrier(0);
    f16x8 af[2], bf[4];
#pragma unroll
    for (int m = 0; m < 2; ++m)
      af[m] = *reinterpret_cast<const f16x8*>(&Asb[cur][ar + m * 16 * 32]);
#pragma unroll
    for (int n = 0; n < 4; ++n)
      bf[n] = *reinterpret_cast<const f16x8*>(&Bsb[cur][br + n * 16 * 32]);
    __builtin_amdgcn_s_setprio(1);
#pragma unroll
    for (int m = 0; m < 2; ++m)
#pragma unroll
      for (int n = 0; n < 4; ++n)
        acc[m][n] =
            __builtin_amdgcn_mfma_f32_16x16x32_f16(af[m], bf[n], acc[m][n], 0, 0, 0);
    __builtin_amdgcn_s_setprio(0);
    asm volatile("" ::: "memory");
    __builtin_amdgcn_s_barrier();
    __builtin_amdgcn_sched_barrier(0);
  }
#undef OSTAGE

#pragma unroll
  for (int m = 0; m < 2; ++m) {
#pragma unroll
    for (int n = 0; n < 4; ++n) {
#pragma unroll
      for (int jr = 0; jr < 4; ++jr) {
        const int rg = row0 + wr * 32 + m * 16 + kg * 4 + jr;
        const int cg = col0 + wc * 64 + n * 16 + rl;
        C[(size_t)rg * N + cg] = acc[m][n][jr] + bias[cg];
      }
    }
  }
}

// --- MFMA flash attention v7: Q-tile 128, 8 waves, image gload_lds staging,
// swapped QK^T, register P, l via ones-MFMA, O^T epilogue (3-step exchange).
__global__ __launch_bounds__(512, 4) void attn_mfma(
    const f16* __restrict__ qkvf, const f16* __restrict__ Kimg,
    const f16* __restrict__ Vimg, const float* __restrict__ cs,
    const float* __restrict__ sn, f16* __restrict__ ao) {
  const int wg = blockIdx.x;
  const int swz = (wg & 7) * 64 + (wg >> 3);  // XCD-contiguous remap (512=8*64)
  const int qb = swz & 15;
  const int hh = (swz >> 4) & 15;
  const int b = swz >> 8;
  const int t = threadIdx.x, l = t & 63, w = t >> 6;
  const int qw = w >> 1, kw = w & 1;
  const int rl = l & 15, kg = l >> 4;

  __shared__ __align__(16) f16 KsB[2][4096];
  __shared__ __align__(16) f16 VtB[2][4096];
  __shared__ float Lbuf[4][2][32];

  const size_t qrow0 = (size_t)(b * Nv + qb * 128 + qw * 32);
  f16x8 bq[2][2];
#pragma unroll
  for (int nq = 0; nq < 2; ++nq)
#pragma unroll
    for (int ks = 0; ks < 2; ++ks)
      bq[nq][ks] = *reinterpret_cast<const f16x8*>(
          &qkvf[(qrow0 + nq * 16 + rl) * QKV3v + hh * DHv + ks * 32 + kg * 8]);

  f16x8 ones;
#pragma unroll
  for (int j = 0; j < 8; ++j) ones[j] = (f16)1.0f;

  const f32x4 zero = {0.f, 0.f, 0.f, 0.f};
  f32x4 o_acc[2][4];
  f32x4 l_acc[2] = {zero, zero};
#pragma unroll
  for (int nq = 0; nq < 2; ++nq)
#pragma unroll
    for (int m2 = 0; m2 < 4; ++m2) o_acc[nq][m2] = zero;

  const size_t ibase = (((size_t)((b * Hv + hh) * 32)) << 12) + w * 512 + l * 8;
  const f16* kimg_t = Kimg + ibase;
  const f16* vimg_t = Vimg + ibase;

#define STAGEI(buf, tile)                                         \
  {                                                               \
    gload16(kimg_t + ((size_t)(tile) << 12), &KsB[buf][w * 512]); \
    gload16(vimg_t + ((size_t)(tile) << 12), &VtB[buf][w * 512]); \
  }

  STAGEI(0, 0);

  const float SC2 = 0.125f * 1.44269504f;

  for (int kt = 0; kt < 32; ++kt) {
    const int cur = kt & 1;
    if (kt + 1 < 32) {
      STAGEI(cur ^ 1, kt + 1);
      asm volatile("s_waitcnt vmcnt(2)" ::: "memory");
    } else {
      asm volatile("s_waitcnt vmcnt(0)" ::: "memory");
    }
    __builtin_amdgcn_s_barrier();
    __builtin_amdgcn_sched_barrier(0);

    const f16* Kc = &KsB[cur][0];
    const f16* Vc = &VtB[cur][0];

    f16x8 ak[2][2];
#pragma unroll
    for (int mk = 0; mk < 2; ++mk)
#pragma unroll
      for (int ks = 0; ks < 2; ++ks)
        ak[mk][ks] = *reinterpret_cast<const f16x8*>(
            &Kc[((kw * 32 + mk * 16 + rl) << 6) |
                ((ks * 32 + kg * 8) ^ ((rl & 7) << 3))]);
    f16x8 av[4];
#pragma unroll
    for (int m2 = 0; m2 < 4; ++m2)
      av[m2] = *reinterpret_cast<const f16x8*>(
          &Vc[((m2 * 16 + rl) << 6) |
              ((kw * 32 + kg * 8) ^ ((rl & 7) << 3))]);

    f32x4 sa[2][2];
#pragma unroll
    for (int mk = 0; mk < 2; ++mk)
#pragma unroll
      for (int nq = 0; nq < 2; ++nq) sa[mk][nq] = zero;
    __builtin_amdgcn_s_setprio(1);
#pragma unroll
    for (int ks = 0; ks < 2; ++ks)
#pragma unroll
      for (int mk = 0; mk < 2; ++mk)
#pragma unroll
        for (int nq = 0; nq < 2; ++nq)
          sa[mk][nq] = __builtin_amdgcn_mfma_f32_16x16x32_f16(
              ak[mk][ks], bq[nq][ks], sa[mk][nq], 0, 0, 0);
    __builtin_amdgcn_s_setprio(0);

    f16x8 pb[2];
#pragma unroll
    for (int nq = 0; nq < 2; ++nq) {
      float p00 = exp2f(fminf(sa[0][nq][0] * SC2, 13.0f));
      float p01 = exp2f(fminf(sa[0][nq][1] * SC2, 13.0f));
      float p02 = exp2f(fminf(sa[0][nq][2] * SC2, 13.0f));
      float p03 = exp2f(fminf(sa[0][nq][3] * SC2, 13.0f));
      float p10 = exp2f(fminf(sa[1][nq][0] * SC2, 13.0f));
      float p11 = exp2f(fminf(sa[1][nq][1] * SC2, 13.0f));
      float p12 = exp2f(fminf(sa[1][nq][2] * SC2, 13.0f));
      float p13 = exp2f(fminf(sa[1][nq][3] * SC2, 13.0f));
      union { hf2 h2[4]; f16x8 v; } u;
      u.h2[0] = __builtin_amdgcn_cvt_pkrtz(p00, p01);
      u.h2[1] = __builtin_amdgcn_cvt_pkrtz(p02, p03);
      u.h2[2] = __builtin_amdgcn_cvt_pkrtz(p10, p11);
      u.h2[3] = __builtin_amdgcn_cvt_pkrtz(p12, p13);
      pb[nq] = u.v;
    }

    __builtin_amdgcn_s_setprio(1);
#pragma unroll
    for (int nq = 0; nq < 2; ++nq)
      l_acc[nq] = __builtin_amdgcn_mfma_f32_16x16x32_f16(
          ones, pb[nq], l_acc[nq], 0, 0, 0);
#pragma unroll
    for (int nq = 0; nq < 2; ++nq)
#pragma unroll
      for (int m2 = 0; m2 < 4; ++m2)
        o_acc[nq][m2] = __builtin_amdgcn_mfma_f32_16x16x32_f16(
            av[m2], pb[nq], o_acc[nq][m2], 0, 0, 0);
    __builtin_amdgcn_s_setprio(0);

    asm volatile("" ::: "memory");
    __builtin_amdgcn_s_barrier();
    __builtin_amdgcn_sched_barrier(0);
  }
#undef STAGEI

  if (kg == 0) {
    Lbuf[qw][kw][rl] = l_acc[0][0];
    Lbuf[qw][kw][16 + rl] = l_acc[1][0];
  }
  char* ob = (qw < 2 ? (char*)KsB : (char*)VtB) + (qw & 1) * 8192;
  if (kw == 1) {
#pragma unroll
    for (int nq = 0; nq < 2; ++nq)
#pragma unroll
      for (int m2 = 0; m2 < 4; ++m2)
        *reinterpret_cast<f32x4*>(
            ob + (nq * 16 + rl) * 256 +
            ((m2 * 64 + kg * 16) ^ ((rl & 7) << 4))) = o_acc[nq][m2];
  }
  __syncthreads();
  if (kw == 0) {
#pragma unroll
    for (int nq = 0; nq < 2; ++nq)
#pragma unroll
      for (int m2 = 0; m2 < 4; ++m2) {
        f32x4* slot = reinterpret_cast<f32x4*>(
            ob + (nq * 16 + rl) * 256 +
            ((m2 * 64 + kg * 16) ^ ((rl & 7) << 4)));
        *slot = *slot + o_acc[nq][m2];
      }
  }
  __syncthreads();
  {
    const int q_local = w * 16 + (l >> 2);
    const int qw_r = q_local >> 5, q_in = q_local & 31;
    const int d0 = (l & 3) * 16;
    char* rb = (qw_r < 2 ? (char*)KsB : (char*)VtB) + (qw_r & 1) * 8192;
    const float linv = 1.0f / (Lbuf[qw_r][0][q_in] + Lbuf[qw_r][1][q_in]);
    const size_t nq_g = (size_t)(b * Nv + qb * 128 + q_local);
    const size_t cb = nq_g * DHv + d0;
    union { f16 e[16]; f16x8 v[2]; } uo;
#pragma unroll
    for (int j = 0; j < 4; ++j) {
      const unsigned off = q_in * 256 + (((l & 3) * 64 + j * 16) ^ ((q_in & 7) << 4));
      const f32x4 a = *reinterpret_cast<const f32x4*>(rb + off);
      const float4 csv = *reinterpret_cast<const float4*>(&cs[cb + j * 4]);
      const float4 snv = *reinterpret_cast<const float4*>(&sn[cb + j * 4]);
      const float o0 = a[0] * linv;
      const float o1 = a[1] * linv;
      const float o2 = a[2] * linv;
      const float o3 = a[3] * linv;
      uo.e[j * 4 + 0] = (f16)(o0 * csv.x + o1 * snv.x);
      uo.e[j * 4 + 1] = (f16)(o1 * csv.y - o0 * snv.y);
      uo.e[j * 4 + 2] = (f16)(o2 * csv.z + o3 * snv.z);
      uo.e[j * 4 + 3] = (f16)(o3 * csv.w - o2 * snv.w);
    }
    f16* aop = &ao[nq_g * INNERv + hh * DHv + d0];
    *reinterpret_cast<f16x8*>(aop) = uo.v[0];
    *reinterpret_cast<f16x8*>(aop + 8) = uo.v[1];
  }
}

extern "C" void kernel_launch(void* const* d_in, const int* in_sizes, int n_in,
                              void* d_out, int out_size, void* d_ws, size_t ws_size,
                              hipStream_t stream) {
  (void)in_sizes; (void)n_in; (void)out_size; (void)ws_size;
  const float* x = (const float*)d_in[0];
  const float* rot = (const float*)d_in[1];
  const float* ln_g = (const float*)d_in[2];
  const float* ln_b = (const float*)d_in[3];
  const float* w_qkv = (const float*)d_in[4];
  const float* b_qkv = (const float*)d_in[5];
  const float* w_out = (const float*)d_in[6];
  const float* b_out = (const float*)d_in[7];

  char* p = (char*)d_ws;
  f16* h = (f16*)p;            p += (size_t)Bv * Nv * DIMv * 2;
  float* cs = (float*)p;       p += (size_t)Bv * Nv * DHv * 4;
  float* sn = (float*)p;       p += (size_t)Bv * Nv * DHv * 4;
  f16* wqT = (f16*)p;          p += (size_t)QKV3v * DIMv * 2;
  f16* woT = (f16*)p;          p += (size_t)DIMv * INNERv * 2;
  f16* qkvf = (f16*)p;         p += (size_t)Bv * Nv * QKV3v * 2;
  f16* ao = (f16*)p;           p += (size_t)Bv * Nv * INNERv * 2;
  f16* Kimg = (f16*)p;         p += (size_t)Bv * Hv * 32 * 4096 * 2;
  f16* Vimg = (f16*)p;         p += (size_t)Bv * Hv * 32 * 4096 * 2;

  ln_kernel<<<dim3(Bv * Nv), dim3(256), 0, stream>>>(x, ln_g, ln_b, h);
  rotcs_kernel<<<dim3((Bv * Nv * DHv) / 256), dim3(256), 0, stream>>>(
      rot, cs, sn, Bv * Nv * DHv);
  transpose_f16<<<dim3(QKV3v / 64, DIMv / 64), dim3(256), 0, stream>>>(
      w_qkv, wqT, DIMv, QKV3v);
  transpose_f16<<<dim3(INNERv / 64, DIMv / 64), dim3(256), 0, stream>>>(
      w_out, woT, DIMv, INNERv);
  gemm256_qkv<<<dim3(QKV3v / 256, (Bv * Nv) / 256), dim3(512), 0, stream>>>(
      h, wqT, b_qkv, qkvf, Kimg, Vimg, cs, sn);
  attn_mfma<<<dim3(512), dim3(512), 0, stream>>>(qkvf, Kimg, Vimg, cs, sn, ao);
  gemm_out64<<<dim3(DIMv / 128, (Bv * Nv) / 64), dim3(256), 0, stream>>>(
      ao, woT, b_out, (float*)d_out, Bv * Nv, DIMv, INNERv);
}

// Round 19
// 144.042 us; speedup vs baseline: 1.1079x; 1.0342x over previous
//
#include <hip/hip_runtime.h>
#include <hip/hip_bf16.h>

typedef _Float16 f16;
typedef __attribute__((ext_vector_type(4))) float f32x4;
typedef __attribute__((ext_vector_type(8))) _Float16 f16x8;
typedef __attribute__((ext_vector_type(4))) _Float16 f16x4;
typedef __attribute__((ext_vector_type(2))) __fp16 hf2;

#define Bv 2
#define Nv 2048
#define DIMv 1024
#define Hv 16
#define DHv 64
#define INNERv 1024
#define QKV3v 3072

__device__ __forceinline__ void gload16(const void* g, void* l) {
  __builtin_amdgcn_global_load_lds(
      (const __attribute__((address_space(1))) void*)g,
      (__attribute__((address_space(3))) void*)l, 16, 0, 0);
}

// ---------------- LayerNorm: fp32 in -> f16 out ----------------
__global__ __launch_bounds__(256) void ln_kernel(
    const float* __restrict__ x, const float* __restrict__ g,
    const float* __restrict__ bb, f16* __restrict__ h) {
  const int row = blockIdx.x;
  const int t = threadIdx.x;
  const float4 v = reinterpret_cast<const float4*>(x + (size_t)row * DIMv)[t];
  float s = v.x + v.y + v.z + v.w;
  float sq = v.x * v.x + v.y * v.y + v.z * v.z + v.w * v.w;
#pragma unroll
  for (int o = 32; o > 0; o >>= 1) {
    s += __shfl_down(s, o);
    sq += __shfl_down(sq, o);
  }
  __shared__ float red[8];
  __shared__ float musr[2];
  const int wave = t >> 6, lane = t & 63;
  if (lane == 0) { red[wave] = s; red[4 + wave] = sq; }
  __syncthreads();
  if (t == 0) {
    const float S = red[0] + red[1] + red[2] + red[3];
    const float SQ = red[4] + red[5] + red[6] + red[7];
    const float mu = S * (1.0f / DIMv);
    const float var = SQ * (1.0f / DIMv) - mu * mu;
    musr[0] = mu;
    musr[1] = rsqrtf(var + 1e-5f);
  }
  __syncthreads();
  const float mu = musr[0], rs = musr[1];
  const float4 gv = reinterpret_cast<const float4*>(g)[t];
  const float4 bv = reinterpret_cast<const float4*>(bb)[t];
  f16x4 o;
  o.x = (f16)((v.x - mu) * rs * gv.x + bv.x);
  o.y = (f16)((v.y - mu) * rs * gv.y + bv.y);
  o.z = (f16)((v.z - mu) * rs * gv.z + bv.z);
  o.w = (f16)((v.w - mu) * rs * gv.w + bv.w);
  *reinterpret_cast<f16x4*>(&h[(size_t)row * DIMv + t * 4]) = o;
}

// ------------- Precompute cos/sin of rotary freqs -----------
__global__ __launch_bounds__(256) void rotcs_kernel(
    const float* __restrict__ rot, float* __restrict__ c,
    float* __restrict__ s, int n) {
  const int i = blockIdx.x * blockDim.x + threadIdx.x;
  if (i < n) {
    const float f = rot[i];
    c[i] = cosf(f);
    s[i] = sinf(f);
  }
}

// ------------- Transpose + convert: W[K][N] fp32 -> Wt[N][K] f16 -----------
__global__ __launch_bounds__(256) void transpose_f16(
    const float* __restrict__ W, f16* __restrict__ Wt, int K, int N) {
  __shared__ float tile[64][65];
  const int t = threadIdx.x;
  const int n0 = blockIdx.x * 64, k0 = blockIdx.y * 64;
#pragma unroll
  for (int i = 0; i < 16; ++i) {
    const int idx = t + i * 256;
    const int r = idx >> 6, c = idx & 63;
    tile[r][c] = W[(size_t)(k0 + r) * N + n0 + c];
  }
  __syncthreads();
#pragma unroll
  for (int i = 0; i < 16; ++i) {
    const int idx = t + i * 256;
    const int r = idx >> 6, c = idx & 63;
    Wt[(size_t)(n0 + r) * K + k0 + c] = (f16)tile[c][r];
  }
}

// ---- QKV GEMM: 256x256 tile, BK=64, one barrier-pair per K-tile ----------
// 512 thr (8 waves, 2Mx4N). Counted vmcnt(8); both-sides XOR swizzle.
// 1D grid 192 with rectangular XCD remap: each XCD owns a 3-col x 8-row
// rectangle (A 4MB + B 1.5MB ~ L2-resident). Epilogue fuses rotary+scatter.
__global__ __launch_bounds__(512) void gemm256_qkv(
    const f16* __restrict__ A, const f16* __restrict__ Bt,
    const float* __restrict__ bias, f16* __restrict__ qkvf,
    f16* __restrict__ Kimg, f16* __restrict__ Vimg,
    const float* __restrict__ cs, const float* __restrict__ sn) {
  __shared__ __align__(16) f16 Abuf[2][256 * 64];
  __shared__ __align__(16) f16 Bbuf[2][256 * 64];
  const int t = threadIdx.x, l = t & 63, w = t >> 6;
  const int wm = w >> 2, wn = w & 3;
  // rectangular XCD remap (bijective: 8 disjoint 3x8 rects tile 12x16)
  const int wgid = blockIdx.x;
  const int xcd = wgid & 7, idx = wgid >> 3;
  const int bx = (xcd & 3) * 3 + idx / 8;     // col-block 0..11
  const int by = (xcd >> 2) * 8 + (idx & 7);  // row-block 0..15
  const int row0 = by * 256, col0 = bx * 256;
  const int rl = l & 15, kg = l >> 4;

  const int srow = l >> 3;
  const int sgk = ((l & 7) ^ (srow & 7)) * 8;
  const f16* gA = &A[(size_t)(row0 + w * 32 + srow) * 1024 + sgk];
  const f16* gB = &Bt[(size_t)(col0 + w * 32 + srow) * 1024 + sgk];

  const f32x4 zero = {0.f, 0.f, 0.f, 0.f};
  f32x4 acc[8][4];
#pragma unroll
  for (int m = 0; m < 8; ++m)
#pragma unroll
    for (int n = 0; n < 4; ++n) acc[m][n] = zero;

#define STG(buf, kt)                                                         \
  {                                                                          \
    _Pragma("unroll") for (int i = 0; i < 4; ++i)                            \
        gload16(gA + (kt)*64 + i * 8 * 1024,                                 \
                &Abuf[buf][(w * 32 + i * 8) * 64]);                          \
    _Pragma("unroll") for (int i = 0; i < 4; ++i)                            \
        gload16(gB + (kt)*64 + i * 8 * 1024,                                 \
                &Bbuf[buf][(w * 32 + i * 8) * 64]);                          \
  }

  const int nkt = 16;  // K=1024 / 64
  STG(0, 0);

  for (int kt = 0; kt < nkt; ++kt) {
    const int cur = kt & 1;
    if (kt + 1 < nkt) {
      STG(cur ^ 1, kt + 1);
      asm volatile("s_waitcnt vmcnt(8)" ::: "memory");
    } else {
      asm volatile("s_waitcnt vmcnt(0)" ::: "memory");
    }
    __builtin_amdgcn_s_barrier();
    __builtin_amdgcn_sched_barrier(0);
#pragma unroll
    for (int kh = 0; kh < 2; ++kh) {
      f16x8 bf[4], af[8];
#pragma unroll
      for (int n = 0; n < 4; ++n) {
        const int r = wn * 64 + n * 16 + rl;
        bf[n] = *reinterpret_cast<const f16x8*>(
            &Bbuf[cur][r * 64 + (((kh * 4 + kg) ^ (r & 7)) << 3)]);
      }
#pragma unroll
      for (int m = 0; m < 8; ++m) {
        const int r = wm * 128 + m * 16 + rl;
        af[m] = *reinterpret_cast<const f16x8*>(
            &Abuf[cur][r * 64 + (((kh * 4 + kg) ^ (r & 7)) << 3)]);
      }
      __builtin_amdgcn_s_setprio(1);
#pragma unroll
      for (int m = 0; m < 8; ++m)
#pragma unroll
        for (int n = 0; n < 4; ++n)
          acc[m][n] = __builtin_amdgcn_mfma_f32_16x16x32_f16(af[m], bf[n],
                                                             acc[m][n], 0, 0, 0);
      __builtin_amdgcn_s_setprio(0);
    }
    asm volatile("" ::: "memory");
    __builtin_amdgcn_s_barrier();
    __builtin_amdgcn_sched_barrier(0);
  }
#undef STG

  // ---- fused epilogue: rotary + scatter to qkvf / Kimg / Vimg ----
  const int slab = col0 >> 10;  // block-uniform: 0=q, 1=k, 2=v
  const int b = row0 >> 11;     // block-uniform
#pragma unroll
  for (int m = 0; m < 8; ++m) {
    const int rg = row0 + wm * 128 + m * 16 + kg * 4;  // +jr
    const int nt = (rg & 2047) >> 6;                   // jr-invariant
#pragma unroll
    for (int n = 0; n < 4; ++n) {
      const int cg = col0 + wn * 64 + n * 16 + rl;
      const int d = cg & 63;
      const int hh = (cg >> 6) & 15;
      float y[4];
#pragma unroll
      for (int jr = 0; jr < 4; ++jr) {
        const float v = acc[m][n][jr] + bias[cg];
        const float p = __shfl_xor(v, 1);
        const size_t cb = (size_t)(rg + jr) * DHv + d;
        const float cc = cs[cb], ss = sn[cb];
        // forward rotary: even d: v*c - p*s ; odd d: v*c + p*s
        y[jr] = (l & 1) ? (v * cc + p * ss) : (v * cc - p * ss);
      }
      if (slab == 0) {
#pragma unroll
        for (int jr = 0; jr < 4; ++jr)
          qkvf[(size_t)(rg + jr) * QKV3v + cg] = (f16)y[jr];
      } else if (slab == 1) {
        const size_t tb = ((size_t)((b * Hv + hh) * 32 + nt)) << 12;
#pragma unroll
        for (int jr = 0; jr < 4; ++jr) {
          const int key = ((m & 3) * 16 + kg * 4 + jr);
          Kimg[tb + key * 64 + (d ^ ((key & 7) << 3))] = (f16)y[jr];
        }
      } else {
        const size_t tb = ((size_t)((b * Hv + hh) * 32 + nt)) << 12;
        const int kp = ((m & 2) << 4) | (kg << 3);  // key' & ~7
        f16x4 pk;
        pk.x = (f16)y[0];
        pk.y = (f16)y[1];
        pk.z = (f16)y[2];
        pk.w = (f16)y[3];
        *reinterpret_cast<f16x4*>(
            &Vimg[tb + d * 64 + (kp ^ ((d & 7) << 3)) + ((m & 1) << 2)]) = pk;
      }
    }
  }
}

// ---- Output projection: 64x128 tile, BK=32, counted vmcnt(3) pipeline ----
__global__ __launch_bounds__(256) void gemm_out64(
    const f16* __restrict__ A, const f16* __restrict__ Bt,
    const float* __restrict__ bias, float* __restrict__ C,
    int M, int N, int K) {
  __shared__ __align__(16) f16 Asb[2][64 * 32];   // 4 KB per buf
  __shared__ __align__(16) f16 Bsb[2][128 * 32];  // 8 KB per buf
  const int t = threadIdx.x;
  const int l = t & 63, w = t >> 6;
  const int wr = w >> 1, wc = w & 1;
  const int row0 = blockIdx.y * 64, col0 = blockIdx.x * 128;

  const f16* ga = &A[(size_t)(row0 + (t >> 2)) * K + (t & 3) * 8];
  const int i2 = t + 256;
  const f16* gb1 = &Bt[(size_t)(col0 + (t >> 2)) * K + (t & 3) * 8];
  const f16* gb2 = &Bt[(size_t)(col0 + (i2 >> 2)) * K + (i2 & 3) * 8];
  const int off1 = w * 512, off2 = w * 512 + 2048;

  const int rl = l & 15, kg = l >> 4;
  const int ar = (wr * 32 + rl) * 32 + kg * 8;
  const int br = (wc * 64 + rl) * 32 + kg * 8;

  const f32x4 zero = {0.f, 0.f, 0.f, 0.f};
  f32x4 acc[2][4];
#pragma unroll
  for (int m = 0; m < 2; ++m)
#pragma unroll
    for (int n = 0; n < 4; ++n) acc[m][n] = zero;

#define OSTAGE(buf, kk)                           \
  {                                               \
    gload16(ga + (kk)*32, &Asb[buf][off1]);       \
    gload16(gb1 + (kk)*32, &Bsb[buf][off1]);      \
    gload16(gb2 + (kk)*32, &Bsb[buf][off2]);      \
  }

  const int nt = K >> 5;
  OSTAGE(0, 0);

  for (int kt = 0; kt < nt; ++kt) {
    const int cur = kt & 1;
    if (kt + 1 < nt) {
      OSTAGE(cur ^ 1, kt + 1);
      asm volatile("s_waitcnt vmcnt(3)" ::: "memory");
    } else {
      asm volatile("s_waitcnt vmcnt(0)" ::: "memory");
    }
    __builtin_amdgcn_s_barrier();
    __builtin_amdgcn_sched_barrier(0);
    f16x8 af[2], bf[4];
#pragma unroll
    for (int m = 0; m < 2; ++m)
      af[m] = *reinterpret_cast<const f16x8*>(&Asb[cur][ar + m * 16 * 32]);
#pragma unroll
    for (int n = 0; n < 4; ++n)
      bf[n] = *reinterpret_cast<const f16x8*>(&Bsb[cur][br + n * 16 * 32]);
    __builtin_amdgcn_s_setprio(1);
#pragma unroll
    for (int m = 0; m < 2; ++m)
#pragma unroll
      for (int n = 0; n < 4; ++n)
        acc[m][n] =
            __builtin_amdgcn_mfma_f32_16x16x32_f16(af[m], bf[n], acc[m][n], 0, 0, 0);
    __builtin_amdgcn_s_setprio(0);
    asm volatile("" ::: "memory");
    __builtin_amdgcn_s_barrier();
    __builtin_amdgcn_sched_barrier(0);
  }
#undef OSTAGE

#pragma unroll
  for (int m = 0; m < 2; ++m) {
#pragma unroll
    for (int n = 0; n < 4; ++n) {
#pragma unroll
      for (int jr = 0; jr < 4; ++jr) {
        const int rg = row0 + wr * 32 + m * 16 + kg * 4 + jr;
        const int cg = col0 + wc * 64 + n * 16 + rl;
        C[(size_t)rg * N + cg] = acc[m][n][jr] + bias[cg];
      }
    }
  }
}

// --- MFMA flash attention v7: Q-tile 128, 8 waves, image gload_lds staging,
// swapped QK^T, register P, l via ones-MFMA, O^T epilogue (3-step exchange).
__global__ __launch_bounds__(512, 4) void attn_mfma(
    const f16* __restrict__ qkvf, const f16* __restrict__ Kimg,
    const f16* __restrict__ Vimg, const float* __restrict__ cs,
    const float* __restrict__ sn, f16* __restrict__ ao) {
  const int wg = blockIdx.x;
  const int swz = (wg & 7) * 64 + (wg >> 3);  // XCD-contiguous remap (512=8*64)
  const int qb = swz & 15;
  const int hh = (swz >> 4) & 15;
  const int b = swz >> 8;
  const int t = threadIdx.x, l = t & 63, w = t >> 6;
  const int qw = w >> 1, kw = w & 1;
  const int rl = l & 15, kg = l >> 4;

  __shared__ __align__(16) f16 KsB[2][4096];
  __shared__ __align__(16) f16 VtB[2][4096];
  __shared__ float Lbuf[4][2][32];

  const size_t qrow0 = (size_t)(b * Nv + qb * 128 + qw * 32);
  f16x8 bq[2][2];
#pragma unroll
  for (int nq = 0; nq < 2; ++nq)
#pragma unroll
    for (int ks = 0; ks < 2; ++ks)
      bq[nq][ks] = *reinterpret_cast<const f16x8*>(
          &qkvf[(qrow0 + nq * 16 + rl) * QKV3v + hh * DHv + ks * 32 + kg * 8]);

  f16x8 ones;
#pragma unroll
  for (int j = 0; j < 8; ++j) ones[j] = (f16)1.0f;

  const f32x4 zero = {0.f, 0.f, 0.f, 0.f};
  f32x4 o_acc[2][4];
  f32x4 l_acc[2] = {zero, zero};
#pragma unroll
  for (int nq = 0; nq < 2; ++nq)
#pragma unroll
    for (int m2 = 0; m2 < 4; ++m2) o_acc[nq][m2] = zero;

  const size_t ibase = (((size_t)((b * Hv + hh) * 32)) << 12) + w * 512 + l * 8;
  const f16* kimg_t = Kimg + ibase;
  const f16* vimg_t = Vimg + ibase;

#define STAGEI(buf, tile)                                         \
  {                                                               \
    gload16(kimg_t + ((size_t)(tile) << 12), &KsB[buf][w * 512]); \
    gload16(vimg_t + ((size_t)(tile) << 12), &VtB[buf][w * 512]); \
  }

  STAGEI(0, 0);

  const float SC2 = 0.125f * 1.44269504f;

  for (int kt = 0; kt < 32; ++kt) {
    const int cur = kt & 1;
    if (kt + 1 < 32) {
      STAGEI(cur ^ 1, kt + 1);
      asm volatile("s_waitcnt vmcnt(2)" ::: "memory");
    } else {
      asm volatile("s_waitcnt vmcnt(0)" ::: "memory");
    }
    __builtin_amdgcn_s_barrier();
    __builtin_amdgcn_sched_barrier(0);

    const f16* Kc = &KsB[cur][0];
    const f16* Vc = &VtB[cur][0];

    f16x8 ak[2][2];
#pragma unroll
    for (int mk = 0; mk < 2; ++mk)
#pragma unroll
      for (int ks = 0; ks < 2; ++ks)
        ak[mk][ks] = *reinterpret_cast<const f16x8*>(
            &Kc[((kw * 32 + mk * 16 + rl) << 6) |
                ((ks * 32 + kg * 8) ^ ((rl & 7) << 3))]);
    f16x8 av[4];
#pragma unroll
    for (int m2 = 0; m2 < 4; ++m2)
      av[m2] = *reinterpret_cast<const f16x8*>(
          &Vc[((m2 * 16 + rl) << 6) |
              ((kw * 32 + kg * 8) ^ ((rl & 7) << 3))]);

    f32x4 sa[2][2];
#pragma unroll
    for (int mk = 0; mk < 2; ++mk)
#pragma unroll
      for (int nq = 0; nq < 2; ++nq) sa[mk][nq] = zero;
    __builtin_amdgcn_s_setprio(1);
#pragma unroll
    for (int ks = 0; ks < 2; ++ks)
#pragma unroll
      for (int mk = 0; mk < 2; ++mk)
#pragma unroll
        for (int nq = 0; nq < 2; ++nq)
          sa[mk][nq] = __builtin_amdgcn_mfma_f32_16x16x32_f16(
              ak[mk][ks], bq[nq][ks], sa[mk][nq], 0, 0, 0);
    __builtin_amdgcn_s_setprio(0);

    f16x8 pb[2];
#pragma unroll
    for (int nq = 0; nq < 2; ++nq) {
      float p00 = exp2f(fminf(sa[0][nq][0] * SC2, 13.0f));
      float p01 = exp2f(fminf(sa[0][nq][1] * SC2, 13.0f));
      float p02 = exp2f(fminf(sa[0][nq][2] * SC2, 13.0f));
      float p03 = exp2f(fminf(sa[0][nq][3] * SC2, 13.0f));
      float p10 = exp2f(fminf(sa[1][nq][0] * SC2, 13.0f));
      float p11 = exp2f(fminf(sa[1][nq][1] * SC2, 13.0f));
      float p12 = exp2f(fminf(sa[1][nq][2] * SC2, 13.0f));
      float p13 = exp2f(fminf(sa[1][nq][3] * SC2, 13.0f));
      union { hf2 h2[4]; f16x8 v; } u;
      u.h2[0] = __builtin_amdgcn_cvt_pkrtz(p00, p01);
      u.h2[1] = __builtin_amdgcn_cvt_pkrtz(p02, p03);
      u.h2[2] = __builtin_amdgcn_cvt_pkrtz(p10, p11);
      u.h2[3] = __builtin_amdgcn_cvt_pkrtz(p12, p13);
      pb[nq] = u.v;
    }

    __builtin_amdgcn_s_setprio(1);
#pragma unroll
    for (int nq = 0; nq < 2; ++nq)
      l_acc[nq] = __builtin_amdgcn_mfma_f32_16x16x32_f16(
          ones, pb[nq], l_acc[nq], 0, 0, 0);
#pragma unroll
    for (int nq = 0; nq < 2; ++nq)
#pragma unroll
      for (int m2 = 0; m2 < 4; ++m2)
        o_acc[nq][m2] = __builtin_amdgcn_mfma_f32_16x16x32_f16(
            av[m2], pb[nq], o_acc[nq][m2], 0, 0, 0);
    __builtin_amdgcn_s_setprio(0);

    asm volatile("" ::: "memory");
    __builtin_amdgcn_s_barrier();
    __builtin_amdgcn_sched_barrier(0);
  }
#undef STAGEI

  if (kg == 0) {
    Lbuf[qw][kw][rl] = l_acc[0][0];
    Lbuf[qw][kw][16 + rl] = l_acc[1][0];
  }
  char* ob = (qw < 2 ? (char*)KsB : (char*)VtB) + (qw & 1) * 8192;
  if (kw == 1) {
#pragma unroll
    for (int nq = 0; nq < 2; ++nq)
#pragma unroll
      for (int m2 = 0; m2 < 4; ++m2)
        *reinterpret_cast<f32x4*>(
            ob + (nq * 16 + rl) * 256 +
            ((m2 * 64 + kg * 16) ^ ((rl & 7) << 4))) = o_acc[nq][m2];
  }
  __syncthreads();
  if (kw == 0) {
#pragma unroll
    for (int nq = 0; nq < 2; ++nq)
#pragma unroll
      for (int m2 = 0; m2 < 4; ++m2) {
        f32x4* slot = reinterpret_cast<f32x4*>(
            ob + (nq * 16 + rl) * 256 +
            ((m2 * 64 + kg * 16) ^ ((rl & 7) << 4)));
        *slot = *slot + o_acc[nq][m2];
      }
  }
  __syncthreads();
  {
    const int q_local = w * 16 + (l >> 2);
    const int qw_r = q_local >> 5, q_in = q_local & 31;
    const int d0 = (l & 3) * 16;
    char* rb = (qw_r < 2 ? (char*)KsB : (char*)VtB) + (qw_r & 1) * 8192;
    const float linv = 1.0f / (Lbuf[qw_r][0][q_in] + Lbuf[qw_r][1][q_in]);
    const size_t nq_g = (size_t)(b * Nv + qb * 128 + q_local);
    const size_t cb = nq_g * DHv + d0;
    union { f16 e[16]; f16x8 v[2]; } uo;
#pragma unroll
    for (int j = 0; j < 4; ++j) {
      const unsigned off = q_in * 256 + (((l & 3) * 64 + j * 16) ^ ((q_in & 7) << 4));
      const f32x4 a = *reinterpret_cast<const f32x4*>(rb + off);
      const float4 csv = *reinterpret_cast<const float4*>(&cs[cb + j * 4]);
      const float4 snv = *reinterpret_cast<const float4*>(&sn[cb + j * 4]);
      const float o0 = a[0] * linv;
      const float o1 = a[1] * linv;
      const float o2 = a[2] * linv;
      const float o3 = a[3] * linv;
      uo.e[j * 4 + 0] = (f16)(o0 * csv.x + o1 * snv.x);
      uo.e[j * 4 + 1] = (f16)(o1 * csv.y - o0 * snv.y);
      uo.e[j * 4 + 2] = (f16)(o2 * csv.z + o3 * snv.z);
      uo.e[j * 4 + 3] = (f16)(o3 * csv.w - o2 * snv.w);
    }
    f16* aop = &ao[nq_g * INNERv + hh * DHv + d0];
    *reinterpret_cast<f16x8*>(aop) = uo.v[0];
    *reinterpret_cast<f16x8*>(aop + 8) = uo.v[1];
  }
}

extern "C" void kernel_launch(void* const* d_in, const int* in_sizes, int n_in,
                              void* d_out, int out_size, void* d_ws, size_t ws_size,
                              hipStream_t stream) {
  (void)in_sizes; (void)n_in; (void)out_size; (void)ws_size;
  const float* x = (const float*)d_in[0];
  const float* rot = (const float*)d_in[1];
  const float* ln_g = (const float*)d_in[2];
  const float* ln_b = (const float*)d_in[3];
  const float* w_qkv = (const float*)d_in[4];
  const float* b_qkv = (const float*)d_in[5];
  const float* w_out = (const float*)d_in[6];
  const float* b_out = (const float*)d_in[7];

  char* p = (char*)d_ws;
  f16* h = (f16*)p;            p += (size_t)Bv * Nv * DIMv * 2;
  float* cs = (float*)p;       p += (size_t)Bv * Nv * DHv * 4;
  float* sn = (float*)p;       p += (size_t)Bv * Nv * DHv * 4;
  f16* wqT = (f16*)p;          p += (size_t)QKV3v * DIMv * 2;
  f16* woT = (f16*)p;          p += (size_t)DIMv * INNERv * 2;
  f16* qkvf = (f16*)p;         p += (size_t)Bv * Nv * QKV3v * 2;
  f16* ao = (f16*)p;           p += (size_t)Bv * Nv * INNERv * 2;
  f16* Kimg = (f16*)p;         p += (size_t)Bv * Hv * 32 * 4096 * 2;
  f16* Vimg = (f16*)p;         p += (size_t)Bv * Hv * 32 * 4096 * 2;

  ln_kernel<<<dim3(Bv * Nv), dim3(256), 0, stream>>>(x, ln_g, ln_b, h);
  rotcs_kernel<<<dim3((Bv * Nv * DHv) / 256), dim3(256), 0, stream>>>(
      rot, cs, sn, Bv * Nv * DHv);
  transpose_f16<<<dim3(QKV3v / 64, DIMv / 64), dim3(256), 0, stream>>>(
      w_qkv, wqT, DIMv, QKV3v);
  transpose_f16<<<dim3(INNERv / 64, DIMv / 64), dim3(256), 0, stream>>>(
      w_out, woT, DIMv, INNERv);
  gemm256_qkv<<<dim3(192), dim3(512), 0, stream>>>(
      h, wqT, b_qkv, qkvf, Kimg, Vimg, cs, sn);
  attn_mfma<<<dim3(512), dim3(512), 0, stream>>>(qkvf, Kimg, Vimg, cs, sn, ao);
  gemm_out64<<<dim3(DIMv / 128, (Bv * Nv) / 64), dim3(256), 0, stream>>>(
      ao, woT, b_out, (float*)d_out, Bv * Nv, DIMv, INNERv);
}